// Round 1
// baseline (294.156 us; speedup 1.0000x reference)
//
#include <hip/hip_runtime.h>

#define NQ    12
#define BATCH 8192

// One wave (64 lanes) simulates one batch element's 4096-dim real state:
// d = (lane << 6) | r  -> bits 0..5 of d are the per-lane register index r,
//                         bits 6..11 of d are the lane index.
__global__ __launch_bounds__(256, 4)
void qc_kernel(const float* __restrict__ x, const float* __restrict__ theta,
               float* __restrict__ out) {
    const int lane = threadIdx.x & 63;
    const int b = (blockIdx.x << 2) + (threadIdx.x >> 6);

    float v[64];

    // ---- initial layer: product state  amp[d] = prod_q (bit_q ? sin : cos)(x_q/2)
    float L = 1.0f;
    #pragma unroll
    for (int q = 6; q < NQ; ++q) {
        float ang = 0.5f * x[b * NQ + q];
        float s, c;
        __sincosf(ang, &s, &c);
        L *= ((lane >> (q - 6)) & 1) ? s : c;
    }
    v[0] = L;
    #pragma unroll
    for (int q = 0; q < 6; ++q) {
        float ang = 0.5f * x[b * NQ + q];
        float s, c;
        __sincosf(ang, &s, &c);
        #pragma unroll
        for (int r = 0; r < (1 << q); ++r) {
            v[r + (1 << q)] = v[r] * s;   // bit q = 1
            v[r]            = v[r] * c;   // bit q = 0
        }
    }

    // ---- 4 theta layers: 12 RY gates then the CNOT ring permutation
    #pragma unroll 1
    for (int layer = 0; layer < 4; ++layer) {
        // RY on in-register qubits 0..5
        #pragma unroll
        for (int q = 0; q < 6; ++q) {
            float ang = 0.5f * theta[layer * NQ + q];
            float s, c;
            __sincosf(ang, &s, &c);
            #pragma unroll
            for (int r0 = 0; r0 < 64; ++r0) {
                if (r0 & (1 << q)) continue;
                const int r1 = r0 | (1 << q);
                float a0 = v[r0], a1 = v[r1];
                v[r0] = c * a0 - s * a1;
                v[r1] = s * a0 + c * a1;
            }
        }
        // RY on lane qubits 6..11 (cross-lane)
        #pragma unroll
        for (int q = 6; q < NQ; ++q) {
            float ang = 0.5f * theta[layer * NQ + q];
            float s, c;
            __sincosf(ang, &s, &c);
            const int m = 1 << (q - 6);
            const float sgn = (lane & m) ? s : -s;   // bit=1: +s*other ; bit=0: -s*other
            #pragma unroll
            for (int r = 0; r < 64; ++r) {
                float o = __shfl_xor(v[r], m, 64);
                v[r] = fmaf(sgn, o, c * v[r]);
            }
        }
        // ---- ring permutation: gather by CNOT(0,1), CNOT(1,2), ..., CNOT(11,0)
        // CNOT(c,t), c,t both register bits (0..4 -> 1..5): static register swap
        #pragma unroll
        for (int cq = 0; cq < 5; ++cq) {
            const int t = cq + 1;
            #pragma unroll
            for (int r = 0; r < 64; ++r) {
                if (((r >> cq) & 1) && !((r >> t) & 1)) {
                    float tmp = v[r];
                    v[r] = v[r | (1 << t)];
                    v[r | (1 << t)] = tmp;
                }
            }
        }
        // CNOT(5,6): control = reg bit 5, target = lane bit 0
        #pragma unroll
        for (int r = 32; r < 64; ++r)          // regs with bit5 = 1
            v[r] = __shfl_xor(v[r], 1, 64);
        // CNOT(6,7)..(10,11): both lane bits
        #pragma unroll
        for (int cq = 6; cq < 11; ++cq) {
            const int cm = 1 << (cq - 6);
            const int tm = 1 << (cq - 5);
            const bool cond = (lane & cm) != 0;
            #pragma unroll
            for (int r = 0; r < 64; ++r) {
                float o = __shfl_xor(v[r], tm, 64);
                v[r] = cond ? o : v[r];
            }
        }
        // CNOT(11,0): control = lane bit 5, target = reg bit 0
        {
            const bool cond = (lane & 32) != 0;
            #pragma unroll
            for (int r = 0; r < 64; r += 2) {
                float lo = v[r], hi = v[r + 1];
                v[r]     = cond ? hi : lo;
                v[r + 1] = cond ? lo : hi;
            }
        }
    }

    // ---- epilogue: out[b,q] = sum_d v[d]^2 * (1 - 2*bit_q(d))
    float tot = 0.0f;
    float Aq[6] = {0.f, 0.f, 0.f, 0.f, 0.f, 0.f};  // sums over regs with bit q = 1
    #pragma unroll
    for (int r = 0; r < 64; ++r) {
        float p = v[r] * v[r];
        tot += p;
        #pragma unroll
        for (int q = 0; q < 6; ++q)
            if ((r >> q) & 1) Aq[q] += p;
    }
    float res[NQ];
    #pragma unroll
    for (int q = 0; q < 6; ++q) res[q] = tot - 2.0f * Aq[q];
    #pragma unroll
    for (int q = 6; q < NQ; ++q) res[q] = ((lane >> (q - 6)) & 1) ? -tot : tot;

    #pragma unroll
    for (int q = 0; q < NQ; ++q) {
        float r = res[q];
        #pragma unroll
        for (int m = 1; m < 64; m <<= 1) r += __shfl_xor(r, m, 64);
        res[q] = r;
    }
    if (lane == 0) {
        #pragma unroll
        for (int q = 0; q < NQ; ++q) out[b * NQ + q] = res[q];
    }
}

extern "C" void kernel_launch(void* const* d_in, const int* in_sizes, int n_in,
                              void* d_out, int out_size, void* d_ws, size_t ws_size,
                              hipStream_t stream) {
    const float* x     = (const float*)d_in[0];
    const float* theta = (const float*)d_in[1];
    float* out = (float*)d_out;
    dim3 grid(BATCH / 4), block(256);
    qc_kernel<<<grid, block, 0, stream>>>(x, theta, out);
}

// Round 2
// 165.014 us; speedup vs baseline: 1.7826x; 1.7826x over previous
//
#include <hip/hip_runtime.h>

#define NQ    12
#define BATCH 8192

// One wave (64 lanes) simulates one batch element's 4096-dim real state:
// d = (lane << 6) | r  -> bits 0..5 of d are the per-lane register index r,
//                         bits 6..11 of d are the lane index.
// The imaginary part is identically zero (RY is real, perms are real).
__global__ __launch_bounds__(256, 2)
void qc_kernel(const float* __restrict__ x, const float* __restrict__ theta,
               float* __restrict__ out) {
    const int lane = threadIdx.x & 63;
    const int b = (blockIdx.x << 2) + (threadIdx.x >> 6);

    float v[64];

    // ---- initial layer: product state  amp[d] = prod_q (bit_q ? sin : cos)(x_q/2)
    float L = 1.0f;
    #pragma unroll
    for (int q = 6; q < NQ; ++q) {
        float ang = 0.5f * x[b * NQ + q];
        float s, c;
        __sincosf(ang, &s, &c);
        L *= ((lane >> (q - 6)) & 1) ? s : c;
    }
    v[0] = L;
    #pragma unroll
    for (int q = 0; q < 6; ++q) {
        float ang = 0.5f * x[b * NQ + q];
        float s, c;
        __sincosf(ang, &s, &c);
        #pragma unroll
        for (int r = 0; r < (1 << q); ++r) {
            v[r + (1 << q)] = v[r] * s;   // bit q = 1
            v[r]            = v[r] * c;   // bit q = 0
        }
    }

    // combined lane-gather index for the ring permutation:
    // CNOT(6,7)..(10,11) compose to src(l) = l ^ ((l & 31) << 1)
    const int srcl = lane ^ ((lane & 31) << 1);

    // ---- 4 theta layers: 12 RY gates then the CNOT ring permutation
    #pragma unroll 1
    for (int layer = 0; layer < 4; ++layer) {
        // RY on in-register qubits 0..5
        #pragma unroll
        for (int q = 0; q < 6; ++q) {
            float ang = 0.5f * theta[layer * NQ + q];
            float s, c;
            __sincosf(ang, &s, &c);
            #pragma unroll
            for (int r0 = 0; r0 < 64; ++r0) {
                if (r0 & (1 << q)) continue;
                const int r1 = r0 | (1 << q);
                float a0 = v[r0], a1 = v[r1];
                v[r0] = c * a0 - s * a1;
                v[r1] = s * a0 + c * a1;
            }
        }
        // RY on lane qubits 6..11 (cross-lane, __shfl_xor)
        #pragma unroll
        for (int q = 6; q < NQ; ++q) {
            float ang = 0.5f * theta[layer * NQ + q];
            float s, c;
            __sincosf(ang, &s, &c);
            const int m = 1 << (q - 6);
            const float sgn = (lane & m) ? s : -s;   // bit=1: +s*other ; bit=0: -s*other
            #pragma unroll
            for (int r = 0; r < 64; ++r) {
                float o = __shfl_xor(v[r], m, 64);
                v[r] = fmaf(sgn, o, c * v[r]);
            }
        }
        // ---- ring permutation, fused:
        // reg-bit CNOTs (0,1)..(4,5): static renaming rsrc(r) = r ^ ((r&31)<<1)
        // CNOT(5,6) + lane CNOTs (6,7)..(10,11): one bpermute,
        //   src lane = srcl ^ bit5(current reg index)
        float t[64];
        #pragma unroll
        for (int r = 0; r < 64; ++r) t[r] = v[r ^ ((r & 31) << 1)];
        #pragma unroll
        for (int r = 0; r < 64; ++r)
            v[r] = __shfl(t[r], srcl ^ (r >> 5), 64);
        // CNOT(11,0): control = lane bit 5, target = reg bit 0 (pair swap)
        const bool c11 = (lane & 32) != 0;
        #pragma unroll
        for (int r = 0; r < 64; r += 2) {
            float lo = v[r], hi = v[r + 1];
            v[r]     = c11 ? hi : lo;
            v[r + 1] = c11 ? lo : hi;
        }
    }

    // ---- epilogue: out[b,q] = sum_d v[d]^2 * (1 - 2*bit_q(d))
    float tot = 0.0f;
    float Aq[6] = {0.f, 0.f, 0.f, 0.f, 0.f, 0.f};  // sums over regs with bit q = 1
    #pragma unroll
    for (int r = 0; r < 64; ++r) {
        float p = v[r] * v[r];
        tot += p;
        #pragma unroll
        for (int q = 0; q < 6; ++q)
            if ((r >> q) & 1) Aq[q] += p;
    }
    float res[NQ];
    #pragma unroll
    for (int q = 0; q < 6; ++q) res[q] = tot - 2.0f * Aq[q];
    #pragma unroll
    for (int q = 6; q < NQ; ++q) res[q] = ((lane >> (q - 6)) & 1) ? -tot : tot;

    #pragma unroll
    for (int q = 0; q < NQ; ++q) {
        float r = res[q];
        #pragma unroll
        for (int m = 1; m < 64; m <<= 1) r += __shfl_xor(r, m, 64);
        res[q] = r;
    }
    if (lane == 0) {
        #pragma unroll
        for (int q = 0; q < NQ; ++q) out[b * NQ + q] = res[q];
    }
}

extern "C" void kernel_launch(void* const* d_in, const int* in_sizes, int n_in,
                              void* d_out, int out_size, void* d_ws, size_t ws_size,
                              hipStream_t stream) {
    const float* x     = (const float*)d_in[0];
    const float* theta = (const float*)d_in[1];
    float* out = (float*)d_out;
    dim3 grid(BATCH / 4), block(256);
    qc_kernel<<<grid, block, 0, stream>>>(x, theta, out);
}

// Round 3
// 126.618 us; speedup vs baseline: 2.3232x; 1.3032x over previous
//
#include <hip/hip_runtime.h>

#define NQ    12
#define BATCH 8192

// ---------------------------------------------------------------------------
// One wave (64 lanes) simulates one batch element's 4096-dim real state:
// d = (lane << 6) | reg. Imag part is identically zero (RY real, perms real).
//
// The per-layer ring permutation (12 CNOTs) is GF(2)-linear:
//   reg part  rho(r) = r ^ ((r&31)<<1)   (deferred: compile-time reg renaming)
//   lane part sig(l) = l ^ ((l&31)<<1)   (deferred: butterfly masks become
//                                         sig^t(m), conditions become parities
//                                         of rows of sig^-t)
// plus CNOT(5,6) (reg-bit5 -> lane xor) and CNOT(11,0) (lane-cond reg swap),
// which are executed explicitly with renamed indices/masks.
// ---------------------------------------------------------------------------

constexpr int sig6(int x)            { return (x ^ (x << 1)) & 63; }
constexpr int sigpow6(int x, int t)  { return t == 0 ? x : sigpow6(sig6(x), t - 1); }
// bit_j(sig^-t(p)) = parity(p & rowmask6(j,t));  sig^8 = I  ->  sig^-t = sig^(8-t)
constexpr int rowmask6(int j, int t) {
    int tt = (8 - (t % 8)) % 8;
    int m = 0;
    for (int i = 0; i < 6; ++i)
        if ((sigpow6(1 << i, tt) >> j) & 1) m |= 1 << i;
    return m;
}

// ---- cross-lane xor-butterfly helpers (no ds_bpermute!) -------------------
template<int C>
__device__ __forceinline__ float dppf(float x) {
    return __int_as_float(__builtin_amdgcn_mov_dpp(__float_as_int(x), C, 0xF, 0xF, true));
}

// o[l] = x[l ^ M].  DPP for masks {1,2,3,7,15}, ds_swizzle for other lo-masks,
// permlane32_swap (+add/sub, selection-free) for the bit-5 crossing.
template<int M>
__device__ __forceinline__ float shx(float x) {
    static_assert(M > 0 && M < 64, "mask");
    constexpr int lo = M & 31;
    float y = x;
    if constexpr (lo == 1)       y = dppf<0xB1>(y);          // quad_perm [1,0,3,2]
    else if constexpr (lo == 2)  y = dppf<0x4E>(y);          // quad_perm [2,3,0,1]
    else if constexpr (lo == 3)  y = dppf<0x1B>(y);          // quad_perm [3,2,1,0]
    else if constexpr (lo == 7)  y = dppf<0x141>(y);         // row_half_mirror
    else if constexpr (lo == 15) y = dppf<0x140>(y);         // row_mirror
    else if constexpr (lo != 0)
        y = __int_as_float(__builtin_amdgcn_ds_swizzle(__float_as_int(y),
                                                       0x1F | (lo << 10)));
    if constexpr ((M & 32) != 0) {
        int yi = __float_as_int(y);
        auto p = __builtin_amdgcn_permlane32_swap(yi, yi, false, false);
        // p holds {v_lo,v_lo} and {v_hi,v_hi} in some order: p0+p1 = y[l]+y[l^32]
        y = (__int_as_float(p[0]) + __int_as_float(p[1])) - y;
    }
    return y;
}

__device__ __forceinline__ float wave_sum(float x) {
    x += dppf<0xB1>(x);
    x += dppf<0x4E>(x);
    x += __int_as_float(__builtin_amdgcn_ds_swizzle(__float_as_int(x), 0x1F | (4 << 10)));
    x += __int_as_float(__builtin_amdgcn_ds_swizzle(__float_as_int(x), 0x1F | (8 << 10)));
    x += __int_as_float(__builtin_amdgcn_ds_swizzle(__float_as_int(x), 0x1F | (16 << 10)));
    int xi = __float_as_int(x);
    auto p = __builtin_amdgcn_permlane32_swap(xi, xi, false, false);
    return __int_as_float(p[0]) + __int_as_float(p[1]);
}

// ---- gate building blocks (T = number of completed ring layers) -----------
template<int T, int Q>   // RY on current reg qubit Q; reg renaming A = rho^T
__device__ __forceinline__ void regRY(float* v, float s, float c) {
    constexpr int D = sigpow6(1 << Q, T);
    #pragma unroll
    for (int r0 = 0; r0 < 64; ++r0) {
        if (r0 & (1 << Q)) continue;
        const int p0 = sigpow6(r0, T);
        const int p1 = p0 ^ D;
        float a0 = v[p0], a1 = v[p1];
        v[p0] = fmaf(c, a0, -(s * a1));
        v[p1] = fmaf(c, a1,  (s * a0));
    }
}

template<int T, int J>   // RY on current lane qubit J (qubit 6+J)
__device__ __forceinline__ void laneRY(float* v, float s, float c, int lane) {
    constexpr int M  = sigpow6(1 << J, T);   // physical butterfly mask
    constexpr int RM = rowmask6(J, T);       // parity mask for current bit J
    const float sgn = (__popc(lane & RM) & 1) ? s : -s;
    #pragma unroll
    for (int r = 0; r < 64; ++r) {
        float o = shx<M>(v[r]);
        v[r] = fmaf(sgn, o, c * v[r]);
    }
}

template<int T>          // CNOT(5,6): current reg bit5 controls lane xor(1)
__device__ __forceinline__ void c56(float* v) {
    constexpr int ML = sigpow6(1, T);        // physical lane mask (1,3,5,15)
    #pragma unroll
    for (int r = 32; r < 64; ++r) {          // current reg index, bit5 = 1
        const int pr = sigpow6(r, T + 1);    // A = rho^(T+1) (post-rename)
        v[pr] = shx<ML>(v[pr]);
    }
}

template<int T>          // CNOT(11,0): current lane bit5 controls reg-bit0 swap
__device__ __forceinline__ void c110(float* v, int lane) {
    const bool cond = (__popc(lane & rowmask6(5, T + 1)) & 1) != 0;
    constexpr int D = sigpow6(1, T + 1);
    #pragma unroll
    for (int r = 0; r < 64; r += 2) {
        const int a0 = sigpow6(r, T + 1);
        const int a1 = a0 ^ D;
        float x0 = v[a0], x1 = v[a1];
        v[a0] = cond ? x1 : x0;
        v[a1] = cond ? x0 : x1;
    }
}

template<int T>
__device__ __forceinline__ void do_layer(float* v, const float* __restrict__ theta,
                                         int lane) {
    float s, c;
    __sincosf(0.5f * theta[T * NQ + 0], &s, &c); regRY<T, 0>(v, s, c);
    __sincosf(0.5f * theta[T * NQ + 1], &s, &c); regRY<T, 1>(v, s, c);
    __sincosf(0.5f * theta[T * NQ + 2], &s, &c); regRY<T, 2>(v, s, c);
    __sincosf(0.5f * theta[T * NQ + 3], &s, &c); regRY<T, 3>(v, s, c);
    __sincosf(0.5f * theta[T * NQ + 4], &s, &c); regRY<T, 4>(v, s, c);
    __sincosf(0.5f * theta[T * NQ + 5], &s, &c); regRY<T, 5>(v, s, c);
    __sincosf(0.5f * theta[T * NQ + 6],  &s, &c); laneRY<T, 0>(v, s, c, lane);
    __sincosf(0.5f * theta[T * NQ + 7],  &s, &c); laneRY<T, 1>(v, s, c, lane);
    __sincosf(0.5f * theta[T * NQ + 8],  &s, &c); laneRY<T, 2>(v, s, c, lane);
    __sincosf(0.5f * theta[T * NQ + 9],  &s, &c); laneRY<T, 3>(v, s, c, lane);
    __sincosf(0.5f * theta[T * NQ + 10], &s, &c); laneRY<T, 4>(v, s, c, lane);
    __sincosf(0.5f * theta[T * NQ + 11], &s, &c); laneRY<T, 5>(v, s, c, lane);
    // ring: reg-rename and lane-gather are deferred (A,B advance to power T+1)
    c56<T>(v);
    c110<T>(v, lane);
}

__global__ __launch_bounds__(256, 3)
void qc_kernel(const float* __restrict__ x, const float* __restrict__ theta,
               float* __restrict__ out) {
    const int lane = threadIdx.x & 63;
    const int b = (blockIdx.x << 2) + (threadIdx.x >> 6);

    float v[64];

    // ---- initial product state: amp[d] = prod_q (bit_q(d) ? sin : cos)(x_q/2)
    float L = 1.0f;
    #pragma unroll
    for (int q = 6; q < NQ; ++q) {
        float s, c;
        __sincosf(0.5f * x[b * NQ + q], &s, &c);
        L *= ((lane >> (q - 6)) & 1) ? s : c;
    }
    v[0] = L;
    #pragma unroll
    for (int q = 0; q < 6; ++q) {
        float s, c;
        __sincosf(0.5f * x[b * NQ + q], &s, &c);
        #pragma unroll
        for (int r = 0; r < (1 << q); ++r) {
            v[r + (1 << q)] = v[r] * s;
            v[r]            = v[r] * c;
        }
    }

    do_layer<0>(v, theta, lane);
    do_layer<1>(v, theta, lane);
    do_layer<2>(v, theta, lane);
    do_layer<3>(v, theta, lane);

    // ---- epilogue: out[b,q] = sum_d v[d]^2 * (1 - 2*bit_q(d))
    // phys reg r holds current reg index rho^-4(r) = rho^4(r);
    // current lane bit j = parity(phys_lane & rowmask6(j,4)).
    float tot = 0.f;
    float A0 = 0.f, A1 = 0.f, A2 = 0.f, A3 = 0.f, A4 = 0.f, A5 = 0.f;
    #pragma unroll
    for (int r = 0; r < 64; ++r) {
        const int lr = sigpow6(r, 4);
        float p = v[r] * v[r];
        tot += p;
        if (lr & 1)  A0 += p;
        if (lr & 2)  A1 += p;
        if (lr & 4)  A2 += p;
        if (lr & 8)  A3 += p;
        if (lr & 16) A4 += p;
        if (lr & 32) A5 += p;
    }
    float sq[6];
    #pragma unroll
    for (int j = 0; j < 6; ++j) {
        const bool bit = (__popc(lane & rowmask6(j, 4)) & 1) != 0;
        sq[j] = bit ? -tot : tot;
    }

    const float Ts = wave_sum(tot);
    float res[NQ];
    res[0] = Ts - 2.f * wave_sum(A0);
    res[1] = Ts - 2.f * wave_sum(A1);
    res[2] = Ts - 2.f * wave_sum(A2);
    res[3] = Ts - 2.f * wave_sum(A3);
    res[4] = Ts - 2.f * wave_sum(A4);
    res[5] = Ts - 2.f * wave_sum(A5);
    #pragma unroll
    for (int j = 0; j < 6; ++j) res[6 + j] = wave_sum(sq[j]);

    float myres = res[0];
    #pragma unroll
    for (int q = 1; q < NQ; ++q) myres = (lane == q) ? res[q] : myres;
    if (lane < NQ) out[b * NQ + lane] = myres;
}

extern "C" void kernel_launch(void* const* d_in, const int* in_sizes, int n_in,
                              void* d_out, int out_size, void* d_ws, size_t ws_size,
                              hipStream_t stream) {
    const float* x     = (const float*)d_in[0];
    const float* theta = (const float*)d_in[1];
    float* out = (float*)d_out;
    dim3 grid(BATCH / 4), block(256);
    qc_kernel<<<grid, block, 0, stream>>>(x, theta, out);
}

// Round 4
// 100.091 us; speedup vs baseline: 2.9389x; 1.2650x over previous
//
#include <hip/hip_runtime.h>

#define NQ    12
#define BATCH 8192

// ---------------------------------------------------------------------------
// One wave (64 lanes) simulates one batch element's 4096-dim real state:
// d = (lane << 6) | reg. Imag part is identically zero (RY real, perms real).
//
// Ring permutation (12 CNOTs) is GF(2)-linear; reg part rho and lane part sig
// (x -> x ^ ((x&31)<<1)) are deferred via compile-time renaming; CNOT(5,6)
// and CNOT(11,0) are executed explicitly with renamed indices/masks.
//
// RY gates use tan-form: RY(th) = c*[[1,-t],[t,1]], t=tan(th/2). The scalar
// c commutes with everything; G = prod(c) over all 48 theta gates is folded
// into the epilogue as G^2 (outputs are quadratic in the state).
// ---------------------------------------------------------------------------

constexpr int sig6(int x)            { return (x ^ (x << 1)) & 63; }
constexpr int sigpow6(int x, int t)  { return t == 0 ? x : sigpow6(sig6(x), t - 1); }
// bit_j(sig^-t(p)) = parity(p & rowmask6(j,t));  sig^8 = I
constexpr int rowmask6(int j, int t) {
    int tt = (8 - (t % 8)) % 8;
    int m = 0;
    for (int i = 0; i < 6; ++i)
        if ((sigpow6(1 << i, tt) >> j) & 1) m |= 1 << i;
    return m;
}

// ---- cross-lane xor helpers (DPP / ds_swizzle / permlane32_swap) ----------
template<int C>
__device__ __forceinline__ float dppf(float x) {
    return __int_as_float(__builtin_amdgcn_mov_dpp(__float_as_int(x), C, 0xF, 0xF, true));
}

template<int M>
__device__ __forceinline__ float shx(float x) {
    static_assert(M > 0 && M < 64, "mask");
    constexpr int lo = M & 31;
    float y = x;
    if constexpr (lo == 1)       y = dppf<0xB1>(y);          // quad_perm [1,0,3,2]
    else if constexpr (lo == 2)  y = dppf<0x4E>(y);          // quad_perm [2,3,0,1]
    else if constexpr (lo == 3)  y = dppf<0x1B>(y);          // quad_perm [3,2,1,0]
    else if constexpr (lo == 7)  y = dppf<0x141>(y);         // row_half_mirror
    else if constexpr (lo == 15) y = dppf<0x140>(y);         // row_mirror
    else if constexpr (lo != 0)
        y = __int_as_float(__builtin_amdgcn_ds_swizzle(__float_as_int(y),
                                                       0x1F | (lo << 10)));
    if constexpr ((M & 32) != 0) {
        int yi = __float_as_int(y);
        auto p = __builtin_amdgcn_permlane32_swap(yi, yi, false, false);
        y = (__int_as_float(p[0]) + __int_as_float(p[1])) - y;
    }
    return y;
}

__device__ __forceinline__ float wave_sum(float x) {
    x += dppf<0xB1>(x);
    x += dppf<0x4E>(x);
    x += __int_as_float(__builtin_amdgcn_ds_swizzle(__float_as_int(x), 0x1F | (4 << 10)));
    x += __int_as_float(__builtin_amdgcn_ds_swizzle(__float_as_int(x), 0x1F | (8 << 10)));
    x += __int_as_float(__builtin_amdgcn_ds_swizzle(__float_as_int(x), 0x1F | (16 << 10)));
    int xi = __float_as_int(x);
    auto p = __builtin_amdgcn_permlane32_swap(xi, xi, false, false);
    return __int_as_float(p[0]) + __int_as_float(p[1]);
}

// ---- gate building blocks (T = completed ring layers) ---------------------
template<int T, int Q>   // tan-form RY on reg qubit Q (2 fma per pair)
__device__ __forceinline__ void regRY(float* v, float t) {
    constexpr int D = sigpow6(1 << Q, T);
    #pragma unroll
    for (int r0 = 0; r0 < 64; ++r0) {
        if (r0 & (1 << Q)) continue;
        const int p0 = sigpow6(r0, T);
        const int p1 = p0 ^ D;
        float a0 = v[p0], a1 = v[p1];
        v[p0] = fmaf(t, -a1, a0);
        v[p1] = fmaf(t,  a0, a1);
    }
}

template<int T, int J>   // tan-form RY on lane qubit 6+J (shuffle + 1 fma)
__device__ __forceinline__ void laneRY(float* v, float t, int lane) {
    constexpr int M  = sigpow6(1 << J, T);
    constexpr int RM = rowmask6(J, T);
    const float ts = (__popc(lane & RM) & 1) ? t : -t;
    #pragma unroll
    for (int r = 0; r < 64; ++r) {
        float o = shx<M>(v[r]);
        v[r] = fmaf(ts, o, v[r]);
    }
}

template<int T>          // CNOT(5,6): reg bit5 controls lane xor
__device__ __forceinline__ void c56(float* v) {
    constexpr int ML = sigpow6(1, T);
    #pragma unroll
    for (int r = 32; r < 64; ++r) {
        const int pr = sigpow6(r, T + 1);
        v[pr] = shx<ML>(v[pr]);
    }
}

template<int T>          // CNOT(11,0): lane bit5 controls reg-bit0 swap
__device__ __forceinline__ void c110(float* v, int lane) {
    const bool cond = (__popc(lane & rowmask6(5, T + 1)) & 1) != 0;
    constexpr int D = sigpow6(1, T + 1);
    #pragma unroll
    for (int r = 0; r < 64; r += 2) {
        const int a0 = sigpow6(r, T + 1);
        const int a1 = a0 ^ D;
        float x0 = v[a0], x1 = v[a1];
        v[a0] = cond ? x1 : x0;
        v[a1] = cond ? x0 : x1;
    }
}

__device__ __forceinline__ float tanhalf(float ang, float& G) {
    float s, c;
    __sincosf(ang, &s, &c);
    G *= c;
    return s * __builtin_amdgcn_rcpf(c);
}

template<int T>
__device__ __forceinline__ void do_layer(float* v, const float* __restrict__ th,
                                         int lane, float& G) {
    regRY<T, 0>(v, tanhalf(0.5f * th[T * NQ + 0], G));
    regRY<T, 1>(v, tanhalf(0.5f * th[T * NQ + 1], G));
    regRY<T, 2>(v, tanhalf(0.5f * th[T * NQ + 2], G));
    regRY<T, 3>(v, tanhalf(0.5f * th[T * NQ + 3], G));
    regRY<T, 4>(v, tanhalf(0.5f * th[T * NQ + 4], G));
    regRY<T, 5>(v, tanhalf(0.5f * th[T * NQ + 5], G));
    laneRY<T, 0>(v, tanhalf(0.5f * th[T * NQ + 6],  G), lane);
    laneRY<T, 1>(v, tanhalf(0.5f * th[T * NQ + 7],  G), lane);
    laneRY<T, 2>(v, tanhalf(0.5f * th[T * NQ + 8],  G), lane);
    laneRY<T, 3>(v, tanhalf(0.5f * th[T * NQ + 9],  G), lane);
    laneRY<T, 4>(v, tanhalf(0.5f * th[T * NQ + 10], G), lane);
    laneRY<T, 5>(v, tanhalf(0.5f * th[T * NQ + 11], G), lane);
    c56<T>(v);
    c110<T>(v, lane);
}

__global__ __launch_bounds__(256, 3)
void qc_kernel(const float* __restrict__ x, const float* __restrict__ theta,
               float* __restrict__ out) {
    const int lane = threadIdx.x & 63;
    const int b = (blockIdx.x << 2) + (threadIdx.x >> 6);

    float v[64];

    // ---- initial product state (exact s,c form; per-batch angles)
    float L = 1.0f;
    #pragma unroll
    for (int q = 6; q < NQ; ++q) {
        float s, c;
        __sincosf(0.5f * x[b * NQ + q], &s, &c);
        L *= ((lane >> (q - 6)) & 1) ? s : c;
    }
    v[0] = L;
    #pragma unroll
    for (int q = 0; q < 6; ++q) {
        float s, c;
        __sincosf(0.5f * x[b * NQ + q], &s, &c);
        #pragma unroll
        for (int r = 0; r < (1 << q); ++r) {
            v[r + (1 << q)] = v[r] * s;
            v[r]            = v[r] * c;
        }
    }

    float G = 1.0f;   // deferred product of 48 cosines
    do_layer<0>(v, theta, lane, G);
    do_layer<1>(v, theta, lane, G);
    do_layer<2>(v, theta, lane, G);
    do_layer<3>(v, theta, lane, G);

    // ---- epilogue: out[b,q] = G^2 * sum_d v[d]^2 * (1 - 2*bit_q(d))
    // logical reg index L lives at phys index L ^ ((L&3)<<4)  (= sig^4)
    #pragma unroll
    for (int r = 0; r < 64; ++r) v[r] *= v[r];

    float Dq[6];
    float s1[32];
    {
        float d = 0.f;
        #pragma unroll
        for (int k = 0; k < 32; ++k) {
            const int i0 = (2 * k)     ^ (((2 * k)     & 3) << 4);
            const int i1 = (2 * k + 1) ^ (((2 * k + 1) & 3) << 4);
            s1[k] = v[i0] + v[i1];
            d    += v[i0] - v[i1];
        }
        Dq[0] = d;
    }
    #pragma unroll
    for (int j = 1; j < 6; ++j) {
        const int n = 32 >> j;
        float d = 0.f;
        #pragma unroll
        for (int k = 0; k < n; ++k) {
            d    += s1[2 * k] - s1[2 * k + 1];
            s1[k] = s1[2 * k] + s1[2 * k + 1];
        }
        Dq[j] = d;
    }
    float tot = s1[0];

    const float G2 = G * G;
    tot *= G2;
    #pragma unroll
    for (int j = 0; j < 6; ++j) Dq[j] *= G2;

    float res[NQ];
    #pragma unroll
    for (int j = 0; j < 6; ++j) res[j] = wave_sum(Dq[j]);
    #pragma unroll
    for (int j = 0; j < 6; ++j) {
        const bool bit = (__popc(lane & rowmask6(j, 4)) & 1) != 0;
        res[6 + j] = wave_sum(bit ? -tot : tot);
    }

    float myres = res[0];
    #pragma unroll
    for (int q = 1; q < NQ; ++q) myres = (lane == q) ? res[q] : myres;
    if (lane < NQ) out[b * NQ + lane] = myres;
}

extern "C" void kernel_launch(void* const* d_in, const int* in_sizes, int n_in,
                              void* d_out, int out_size, void* d_ws, size_t ws_size,
                              hipStream_t stream) {
    const float* x     = (const float*)d_in[0];
    const float* theta = (const float*)d_in[1];
    float* out = (float*)d_out;
    dim3 grid(BATCH / 4), block(256);
    qc_kernel<<<grid, block, 0, stream>>>(x, theta, out);
}